// Round 1
// 366.382 us; speedup vs baseline: 1.0141x; 1.0141x over previous
//
#include <hip/hip_runtime.h>

// Problem constants (from reference setup_inputs)
constexpr int Vn = 32000;        // vocab
constexpr int Nn = 2048;         // B*T
constexpr unsigned WIDTHu = 64000u;  // 2*V

// Key identity: h_d(i)==h_d(j)  <=>  combined_i == combined_j (mod width)
// (salt cancels), so min-over-depth of the CMS query equals the plain
// collision count of combined mod width. Further, mod 64000:
//   31337      % 64000 = 31337
//   2654435769 % 64000 = 35769
// and in*31337 + tg*35769 < 2.15e9 < 2^32, so u32 arithmetic is exact.

// softplus(x) = max(x,0) + log1p(exp(-|x|)); HW exp/log (abs err ~1e-7)
__device__ inline float softplus_f(float x) {
    return fmaxf(x, 0.0f) + __logf(1.0f + __expf(-fabsf(x)));
}

// One block per row: streaming softplus-sum over V=32000 floats (float4 loads).
// Collision count computed in-block from LDS (salt-cancellation identity),
// hidden under the memory-bound streaming loop.
__global__ __launch_bounds__(256)
void row_kernel(const float* __restrict__ logits,
                const int* __restrict__ targets,
                const int* __restrict__ inputs,
                float* __restrict__ nll_arr,
                float* __restrict__ rank_arr) {
    const int row = blockIdx.x;
    const float* lr = logits + (size_t)row * Vn;
    const float4* l4 = reinterpret_cast<const float4*>(lr);

    __shared__ unsigned short cm_s[Nn];  // combined % 64000 fits u16 (<65536)

    // Phase A: all 2048 "combined mod width" values into LDS (8 per thread;
    // inputs/targets are 16 KB total, L2-resident across all blocks).
    for (int j = threadIdx.x; j < Nn; j += 256) {
        unsigned s = (unsigned)inputs[j] * 31337u + (unsigned)targets[j] * 35769u;
        cm_s[j] = (unsigned short)(s % WIDTHu);
    }

    // Streaming softplus sum (the memory-bound bulk: 128 KB/row)
    float local = 0.0f;
    for (int j = threadIdx.x; j < Vn / 4; j += 256) {
        float4 v = l4[j];
        local += softplus_f(v.x) + softplus_f(v.y) + softplus_f(v.z) + softplus_f(v.w);
    }

    __syncthreads();  // cm_s fully written

    // Phase B: count collisions for this row (== CMS min-query result)
    unsigned my = (unsigned)inputs[row] * 31337u + (unsigned)targets[row] * 35769u;
    const unsigned short myc = (unsigned short)(my % WIDTHu);
    int cnt = 0;
    for (int j = threadIdx.x; j < Nn; j += 256)
        cnt += (cm_s[j] == myc) ? 1 : 0;

    // wave(64) shuffle reduce of {local, cnt}, then cross-wave via LDS
#pragma unroll
    for (int off = 32; off > 0; off >>= 1) {
        local += __shfl_down(local, off, 64);
        cnt   += __shfl_down(cnt, off, 64);
    }
    __shared__ float smem[4];
    __shared__ int   scnt[4];
    if ((threadIdx.x & 63) == 0) {
        smem[threadIdx.x >> 6] = local;
        scnt[threadIdx.x >> 6] = cnt;
    }
    __syncthreads();

    if (threadIdx.x == 0) {
        float S = smem[0] + smem[1] + smem[2] + smem[3];
        int   c = scnt[0] + scnt[1] + scnt[2] + scnt[3];

        float scale = fminf(1.0f / (S + 1e-6f), 1.0f);
        float remainder = fmaxf(1.0f - S * scale, 0.0f);

        int tgt = targets[row];
        bool mask = (tgt != -1);           // always true for this data, kept for fidelity
        int tsafe = mask ? tgt : 0;

        float pt = softplus_f(lr[tsafe]) * scale + (tsafe == 0 ? remainder : 0.0f);
        float p0 = softplus_f(lr[0]) * scale + remainder;

        float lp_t = __logf(fmaxf(pt, 1e-10f));
        nll_arr[row] = mask ? -lp_t : 0.0f;

        float strength = tanhf((float)c * 0.1f);
        float rerr = fmaxf(p0 - pt + 0.1f, 0.0f);
        rank_arr[row] = rerr * strength;
    }
}

__global__ __launch_bounds__(256)
void finalize_kernel(const float* __restrict__ nll_arr,
                     const float* __restrict__ rank_arr,
                     const int* __restrict__ targets,
                     float* __restrict__ out) {
    float nll = 0.0f, rank = 0.0f, cnt = 0.0f;
    for (int i = threadIdx.x; i < Nn; i += 256) {
        nll += nll_arr[i];
        rank += rank_arr[i];
        cnt += (targets[i] != -1) ? 1.0f : 0.0f;
    }
#pragma unroll
    for (int off = 32; off > 0; off >>= 1) {
        nll  += __shfl_down(nll, off, 64);
        rank += __shfl_down(rank, off, 64);
        cnt  += __shfl_down(cnt, off, 64);
    }
    __shared__ float sn[4], sr[4], sc[4];
    if ((threadIdx.x & 63) == 0) {
        int w = threadIdx.x >> 6;
        sn[w] = nll; sr[w] = rank; sc[w] = cnt;
    }
    __syncthreads();
    if (threadIdx.x == 0) {
        float tn = sn[0] + sn[1] + sn[2] + sn[3];
        float tr = sr[0] + sr[1] + sr[2] + sr[3];
        float tc = sc[0] + sc[1] + sc[2] + sc[3];
        float nll_loss   = tn / fmaxf(tc, 1.0f);
        float basis_loss = tr / (float)Nn;
        out[0] = 1.0f * nll_loss + 0.5f * basis_loss;  // ALPHA=1, BETA=0.5
    }
}

extern "C" void kernel_launch(void* const* d_in, const int* in_sizes, int n_in,
                              void* d_out, int out_size, void* d_ws, size_t ws_size,
                              hipStream_t stream) {
    const float* logits  = (const float*)d_in[0];
    const int*   targets = (const int*)d_in[1];
    const int*   inputs  = (const int*)d_in[2];
    // d_in[3] (salts) intentionally unused: salt cancels in the CMS query.

    // ws layout: [float nll_arr (2048)] [float rank_arr (2048)]
    float* nll_arr  = (float*)d_ws;
    float* rank_arr = nll_arr + Nn;

    row_kernel<<<Nn, 256, 0, stream>>>(logits, targets, inputs, nll_arr, rank_arr);
    finalize_kernel<<<1, 256, 0, stream>>>(nll_arr, rank_arr, targets, (float*)d_out);
}